// Round 1
// baseline (3654.053 us; speedup 1.0000x reference)
//
#include <hip/hip_runtime.h>
#include <math.h>

#define TF 40
#define TE 64
#define NTH 256

__global__ __launch_bounds__(NTH)
void autoint_fused(const float* __restrict__ x,
                   const float* __restrict__ Wq, const float* __restrict__ bq,
                   const float* __restrict__ Wk, const float* __restrict__ bk,
                   const float* __restrict__ Wv, const float* __restrict__ bv,
                   const float* __restrict__ Wr, const float* __restrict__ br,
                   const float* __restrict__ gamma, const float* __restrict__ beta,
                   float* __restrict__ out)
{
    // union: cur activations [40][64] (2560 f32)  /  scores [2][40][40] (3200 f32)
    __shared__ float sU[2 * TF * TF];
    __shared__ float sq[TF][TE];
    __shared__ float sk[TF][TE + 1];   // +1 pad: phase-2 reads per-lane rows (stride 64 would be 32-way bank conflict)
    __shared__ float sv[TF][TE];

    const int t    = threadIdx.x;
    const int wave = t >> 6;
    const int lane = t & 63;
    const int e    = lane;
    const size_t base = (size_t)blockIdx.x * (TF * TE);

    // per-lane (column-e) constants, hoisted across both layers
    const float bqv = bq[e], bkv = bk[e], bvv = bv[e], brv = br[e];
    const float gv = gamma[e], btv = beta[e];

    // load x tile into cur (coalesced float4)
    {
        const float4* xb4 = (const float4*)(x + base);
        float4* s4 = (float4*)sU;
        for (int i = t; i < TF * TE / 4; i += NTH) s4[i] = xb4[i];
    }
    __syncthreads();

    const float* __restrict__ Ws[4] = {Wq, Wk, Wv, Wr};
    const float bias[4] = {bqv, bkv, bvv, brv};

    float res_reg[10];

    for (int lay = 0; lay < 2; ++lay) {
        // ---------- P1: q,k,v,res = relu(cur @ W + b) ----------
        // wave owns rows f = wave + 4*i (i<10), lane owns output column e
        float acc[4][10];
        #pragma unroll
        for (int m = 0; m < 4; ++m)
            #pragma unroll
            for (int i = 0; i < 10; ++i) acc[m][i] = 0.f;

        for (int c = 0; c < TE; c += 4) {
            float w[4][4];
            #pragma unroll
            for (int m = 0; m < 4; ++m) {
                #pragma unroll
                for (int j = 0; j < 4; ++j) w[m][j] = Ws[m][(c + j) * TE + e];
            }
            #pragma unroll
            for (int i = 0; i < 10; ++i) {
                const float4 xv = *(const float4*)&sU[(wave + 4 * i) * TE + c];
                #pragma unroll
                for (int m = 0; m < 4; ++m) {
                    acc[m][i] = fmaf(xv.x, w[m][0], acc[m][i]);
                    acc[m][i] = fmaf(xv.y, w[m][1], acc[m][i]);
                    acc[m][i] = fmaf(xv.z, w[m][2], acc[m][i]);
                    acc[m][i] = fmaf(xv.w, w[m][3], acc[m][i]);
                }
            }
        }
        #pragma unroll
        for (int i = 0; i < 10; ++i) {
            const int f = wave + 4 * i;
            sq[f][e]   = fmaxf(acc[0][i] + bias[0], 0.f);
            sk[f][e]   = fmaxf(acc[1][i] + bias[1], 0.f);
            sv[f][e]   = fmaxf(acc[2][i] + bias[2], 0.f);
            res_reg[i] = fmaxf(acc[3][i] + bias[3], 0.f);
        }
        __syncthreads();   // sq/sk/sv visible; cur (sU) reads done -> scores may overwrite

        // ---------- P2: S = qh @ khT / sqrt(32), softmax over g ----------
        // wave -> (h = wave>>1, f = (wave&1)*20 + j), lane = g (40 active)
        {
            const int h = wave >> 1;
            const int fbase = (wave & 1) * 20;
            const int g = lane;
            const int gg = (g < TF) ? g : 0;
            for (int j = 0; j < 20; ++j) {
                const int f = fbase + j;
                float s = 0.f;
                #pragma unroll
                for (int d = 0; d < 32; d += 4) {
                    const float4 qv = *(const float4*)&sq[f][32 * h + d];   // wave-uniform broadcast
                    const float4 kv = *(const float4*)&sk[gg][32 * h + d];  // per-lane row, padded stride
                    s = fmaf(qv.x, kv.x, s); s = fmaf(qv.y, kv.y, s);
                    s = fmaf(qv.z, kv.z, s); s = fmaf(qv.w, kv.w, s);
                }
                s *= 0.17677669529663687f;   // 1/sqrt(32)
                if (g >= TF) s = -INFINITY;
                float m = s;
                #pragma unroll
                for (int off = 32; off; off >>= 1) m = fmaxf(m, __shfl_xor(m, off));
                const float p = __expf(s - m);   // invalid lanes -> exp(-inf) = 0
                float sum = p;
                #pragma unroll
                for (int off = 32; off; off >>= 1) sum += __shfl_xor(sum, off);
                const float inv = 1.0f / sum;
                if (g < TF) sU[h * (TF * TF) + f * TF + g] = p * inv;
            }
        }
        __syncthreads();   // scores visible

        // ---------- P3: O = S @ vh, merge heads, + res, relu ----------
        float vo[10];
        {
            const int h = e >> 5;
            const float* ssrow = &sU[h * (TF * TF)];
            #pragma unroll
            for (int i = 0; i < 10; ++i) vo[i] = 0.f;
            for (int g = 0; g < TF; g += 4) {
                const float v0 = sv[g + 0][e];
                const float v1 = sv[g + 1][e];
                const float v2 = sv[g + 2][e];
                const float v3 = sv[g + 3][e];
                #pragma unroll
                for (int i = 0; i < 10; ++i) {
                    const int f = wave + 4 * i;
                    const float4 sw = *(const float4*)&ssrow[f * TF + g];   // 2-addr broadcast (h split)
                    vo[i] = fmaf(sw.x, v0, vo[i]); vo[i] = fmaf(sw.y, v1, vo[i]);
                    vo[i] = fmaf(sw.z, v2, vo[i]); vo[i] = fmaf(sw.w, v3, vo[i]);
                }
            }
            #pragma unroll
            for (int i = 0; i < 10; ++i) vo[i] = fmaxf(vo[i] + res_reg[i], 0.f);
        }
        __syncthreads();   // all score reads done before sU is overwritten as next cur

        // ---------- P4: LayerNorm over e, write cur / output ----------
        #pragma unroll
        for (int i = 0; i < 10; ++i) {
            const int f = wave + 4 * i;
            const float val = vo[i];
            float s1 = val, s2 = val * val;
            #pragma unroll
            for (int off = 32; off; off >>= 1) {
                s1 += __shfl_xor(s1, off);
                s2 += __shfl_xor(s2, off);
            }
            const float mu  = s1 * (1.0f / 64.0f);
            const float var = s2 * (1.0f / 64.0f) - mu * mu;
            const float y = (val - mu) * rsqrtf(var + 1e-3f) * gv + btv;
            if (lay == 0) sU[f * TE + e] = y;
            else          out[base + f * TE + e] = y;
        }
        if (lay == 0) __syncthreads();
    }
}

extern "C" void kernel_launch(void* const* d_in, const int* in_sizes, int n_in,
                              void* d_out, int out_size, void* d_ws, size_t ws_size,
                              hipStream_t stream) {
    const float* x     = (const float*)d_in[0];
    const float* Wq    = (const float*)d_in[1];
    const float* bq    = (const float*)d_in[2];
    const float* Wk    = (const float*)d_in[3];
    const float* bk    = (const float*)d_in[4];
    const float* Wv    = (const float*)d_in[5];
    const float* bv    = (const float*)d_in[6];
    const float* Wr    = (const float*)d_in[7];
    const float* br    = (const float*)d_in[8];
    const float* gamma = (const float*)d_in[9];
    const float* beta  = (const float*)d_in[10];
    float* outp = (float*)d_out;

    const int B = in_sizes[0] / (TF * TE);
    autoint_fused<<<B, NTH, 0, stream>>>(x, Wq, bq, Wk, bk, Wv, bv, Wr, br, gamma, beta, outp);
}